// Round 11
// baseline (176.754 us; speedup 1.0000x reference)
//
#include <hip/hip_runtime.h>

#define CC 256
#define NN 1024
#define CN (CC*NN)

typedef __attribute__((ext_vector_type(8))) short short8;
typedef __attribute__((ext_vector_type(8))) unsigned short u16x8;
typedef __attribute__((ext_vector_type(4))) float f32x4;

__device__ __forceinline__ unsigned short f2bf(float x) {
  unsigned u = __float_as_uint(x);
  u = u + 0x7fffu + ((u >> 16) & 1u);
  return (unsigned short)(u >> 16);
}
__device__ __forceinline__ float bf2f(unsigned short b) {
  return __uint_as_float(((unsigned)b) << 16);
}
__device__ __forceinline__ void gload_lds16(const unsigned short* g, unsigned short* l) {
  __builtin_amdgcn_global_load_lds(
      (const __attribute__((address_space(1))) unsigned short*)g,
      (__attribute__((address_space(3))) unsigned short*)l, 16, 0, 0);
}

// ---------- prep: q/k proj (z<12: +passthrough out; z>=12: +xT tile), W convert ----------
__global__ __launch_bounds__(256) void prep_kernel(
    const float* __restrict__ x, const float* __restrict__ Wq,
    const float* __restrict__ Wk, const float4* __restrict__ Wv,
    const float4* __restrict__ W1, const float4* __restrict__ W2,
    unsigned short* __restrict__ wv_bf,
    unsigned short* __restrict__ w1_bf, unsigned short* __restrict__ w2_bf,
    unsigned short* __restrict__ xT, unsigned short* __restrict__ xqT,
    unsigned short* __restrict__ xkT, float* __restrict__ out) {
  __shared__ float shbuf[6464];   // Ws 64x65 + xs 64x36 = 6464 floats = 25.9KB
  int bz = blockIdx.x, t = threadIdx.x;
  if (bz < 2048) {
    // grouped q/k projections, 32-wide n-chunks
    float (*Ws)[65] = (float(*)[65])shbuf;               // 64x65
    float (*xs)[36] = (float(*)[36])(shbuf + 64 * 65);   // 64x36
    int z = bz >> 7, g = (bz >> 5) & 3, n0 = (bz & 31) * 32;
    const float* src; const float* W; unsigned short* dst;
    float* po = nullptr;
    int b = 0;
    if (z < 12) {
      src = x + (long)(4 + z) * CN; W = Wq; dst = xqT + (long)z * CN;
      po = out + (long)(4 + z) * CN;
    } else {
      b = z - 12;
      src = x + (long)b * CN; W = Wk; dst = xkT + (long)b * CN;
    }
    int tr = t >> 6, tc = t & 63;
#pragma unroll
    for (int r = 0; r < 16; ++r) {
      int i = tr + r * 4;
      Ws[i][tc] = W[(g * 64 + i) * 64 + tc];
    }
#pragma unroll
    for (int r = 0; r < 8; ++r) {
      int i = r * 8 + (t >> 5);
      int col = t & 31;
      float v = src[(long)(g * 64 + i) * NN + n0 + col];
      xs[i][col] = v;
      if (po) po[(long)(g * 64 + i) * NN + n0 + col] = v;
    }
    __syncthreads();
    int o = tc, qd = tr;   // qd uniform per wave
    float acc[8];
#pragma unroll
    for (int k = 0; k < 8; ++k) acc[k] = 0.f;
    for (int i = 0; i < 64; ++i) {
      float w = Ws[o][i];
      const float4* xr4 = (const float4*)&xs[i][qd * 8];
      float4 a0 = xr4[0], a1 = xr4[1];
      acc[0] += w * a0.x; acc[1] += w * a0.y; acc[2] += w * a0.z; acc[3] += w * a0.w;
      acc[4] += w * a1.x; acc[5] += w * a1.y; acc[6] += w * a1.z; acc[7] += w * a1.w;
    }
#pragma unroll
    for (int k = 0; k < 8; ++k)
      dst[(long)(n0 + qd * 8 + k) * CC + g * 64 + o] = f2bf(acc[k]);
    // z>=12: emit the xT[b][n][c] tile from the already-staged xs (no extra HBM read)
    if (z >= 12) {
      int nl = t >> 3;            // 0..31
      int coff = (t & 7) * 8;     // 0..56
      u16x8 v8;
#pragma unroll
      for (int k = 0; k < 8; ++k) v8[k] = f2bf(xs[coff + k][nl]);
      *(u16x8*)&xT[(long)b * CN + (long)(n0 + nl) * CC + g * 64 + coff] = v8;
    }
  } else {
    // convert Wv (16384) + W1 (65536) + W2 (65536) = 147456 float4s
    int id = (bz - 2048) * 256 + t;
    const float4* s; unsigned short* d; int k;
    if (id < 16384)      { s = Wv; d = wv_bf; k = id; }
    else if (id < 81920) { s = W1; d = w1_bf; k = id - 16384; }
    else                 { s = W2; d = w2_bf; k = id - 81920; }
    float4 v = s[k];
    ushort4 o; o.x = f2bf(v.x); o.y = f2bf(v.y); o.z = f2bf(v.z); o.w = f2bf(v.w);
    *(ushort4*)&d[k * 4] = o;
  }
}

// ---------- attention GEMM: z<64 -> xv projection; z>=64 -> energy + stats ----------
__global__ __launch_bounds__(256) void attn_gemm(
    const unsigned short* __restrict__ xkt, const unsigned short* __restrict__ xqt,
    const unsigned short* __restrict__ wv, const unsigned short* __restrict__ xt,
    const float* __restrict__ bv, unsigned short* __restrict__ E,
    unsigned short* __restrict__ xv, float2* __restrict__ part) {
  __shared__ unsigned short As[128 * 32];
  __shared__ unsigned short Bs[128 * 32];
  int z = blockIdx.x;
  const unsigned short *A, *B;
  unsigned short* Co;
  long i0, j0;
  int q = 0;
  bool isXV = z < 64;
  if (isXV) {
    int b = z >> 4, r = z & 15;
    i0 = (r >> 3) * 128; j0 = (r & 7) * 128;
    A = wv; B = xt + (long)b * CN; Co = xv + (long)b * CN;
  } else {
    int ze = z - 64;
    q = ze >> 6; int r = ze & 63;
    i0 = (r >> 3) * 128; j0 = (r & 7) * 128;
    A = xkt + (long)(q & 3) * CN; B = xqt + (long)q * CN;
    Co = E + (long)q * NN * NN;
  }
  int t = threadIdx.x, w = t >> 6, l = t & 63;
  int wr = w >> 1, wc = w & 1;
  f32x4 acc[4][4];
#pragma unroll
  for (int a = 0; a < 4; ++a)
#pragma unroll
    for (int b = 0; b < 4; ++b) acc[a][b] = (f32x4){0.f, 0.f, 0.f, 0.f};
  int lr = l & 15, lk = (l >> 4) * 8;
  for (int k0 = 0; k0 < 256; k0 += 32) {
#pragma unroll
    for (int it = 0; it < 2; ++it) {
      int chunk = t + it * 256;
      int row = chunk >> 2, kq = chunk & 3;
      gload_lds16(A + (i0 + row) * 256L + k0 + kq * 8, &As[chunk * 8]);
      gload_lds16(B + (j0 + row) * 256L + k0 + kq * 8, &Bs[chunk * 8]);
    }
    __syncthreads();
    short8 af[4], bfr[4];
#pragma unroll
    for (int f = 0; f < 4; ++f) af[f]  = *(const short8*)&As[(wr * 64 + f * 16 + lr) * 32 + lk];
#pragma unroll
    for (int f = 0; f < 4; ++f) bfr[f] = *(const short8*)&Bs[(wc * 64 + f * 16 + lr) * 32 + lk];
#pragma unroll
    for (int fm = 0; fm < 4; ++fm)
#pragma unroll
      for (int fn = 0; fn < 4; ++fn)
        acc[fm][fn] = __builtin_amdgcn_mfma_f32_16x16x32_bf16(af[fm], bfr[fn], acc[fm][fn], 0, 0, 0);
    __syncthreads();
  }
  int li = (l >> 4) * 4, lj = l & 15;
#pragma unroll
  for (int fm = 0; fm < 4; ++fm)
#pragma unroll
    for (int fn = 0; fn < 4; ++fn) {
      long ib = i0 + wr * 64 + fm * 16 + li;
      long j  = j0 + wc * 64 + fn * 16 + lj;
#pragma unroll
      for (int r = 0; r < 4; ++r) {
        float v = acc[fm][fn][r];
        if (isXV) v += bv[ib + r];
        Co[(ib + r) * 1024 + j] = f2bf(v);
      }
    }
  if (!isXV) {
    int chunk = (int)(i0 >> 6) + wr;
#pragma unroll
    for (int fn = 0; fn < 4; ++fn) {
      float mx = -1e30f;
#pragma unroll
      for (int fm = 0; fm < 4; ++fm)
#pragma unroll
        for (int r = 0; r < 4; ++r) mx = fmaxf(mx, acc[fm][fn][r]);
      mx = fmaxf(mx, __shfl_xor(mx, 16));
      mx = fmaxf(mx, __shfl_xor(mx, 32));
      float sm = 0.f;
#pragma unroll
      for (int fm = 0; fm < 4; ++fm)
#pragma unroll
        for (int r = 0; r < 4; ++r) sm += __expf(acc[fm][fn][r] - mx);
      sm += __shfl_xor(sm, 16);
      sm += __shfl_xor(sm, 32);
      if (l < 16) {
        long n = j0 + wc * 64 + fn * 16 + l;
        part[((long)q * 16 + chunk) * NN + n] = make_float2(mx, sm);
      }
    }
  }
}

// ---------- bf16 MFMA GEMM, 128xBN tile (MLP shapes) ----------
template<int BN, int BIASCOL, int RELU>
__global__ __launch_bounds__(256) void mgemm(
    const unsigned short* __restrict__ A, const unsigned short* __restrict__ B,
    unsigned short* __restrict__ Cout, const float* __restrict__ bias,
    int lda, int ldb, int ldc, int K,
    long sA, int amod, long sB, int bmod, long sC) {
  __shared__ unsigned short As[128 * 32];
  __shared__ unsigned short Bs[BN * 32];
  int z = blockIdx.z;
  A += (long)(z % amod) * sA;
  B += (long)(z % bmod) * sB;
  int t = threadIdx.x, w = t >> 6, l = t & 63;
  int wr = w >> 1, wc = w & 1;
  const int WN = BN / 2, FN = BN / 32;
  long i0 = blockIdx.y * 128, j0 = blockIdx.x * BN;
  f32x4 acc[4][FN];
#pragma unroll
  for (int a = 0; a < 4; ++a)
#pragma unroll
    for (int b = 0; b < FN; ++b) acc[a][b] = (f32x4){0.f, 0.f, 0.f, 0.f};
  int lr = l & 15, lk = (l >> 4) * 8;
  for (int k0 = 0; k0 < K; k0 += 32) {
#pragma unroll
    for (int it = 0; it < 2; ++it) {
      int chunk = t + it * 256;
      int row = chunk >> 2, kq = chunk & 3;
      gload_lds16(A + (i0 + row) * (long)lda + k0 + kq * 8, &As[chunk * 8]);
    }
#pragma unroll
    for (int it = 0; it < BN / 64; ++it) {
      int chunk = t + it * 256;
      int row = chunk >> 2, kq = chunk & 3;
      gload_lds16(B + (j0 + row) * (long)ldb + k0 + kq * 8, &Bs[chunk * 8]);
    }
    __syncthreads();
    short8 af[4], bfr[FN];
#pragma unroll
    for (int f = 0; f < 4; ++f)  af[f]  = *(const short8*)&As[(wr * 64 + f * 16 + lr) * 32 + lk];
#pragma unroll
    for (int f = 0; f < FN; ++f) bfr[f] = *(const short8*)&Bs[(wc * WN + f * 16 + lr) * 32 + lk];
#pragma unroll
    for (int fm = 0; fm < 4; ++fm)
#pragma unroll
      for (int fn = 0; fn < FN; ++fn)
        acc[fm][fn] = __builtin_amdgcn_mfma_f32_16x16x32_bf16(af[fm], bfr[fn], acc[fm][fn], 0, 0, 0);
    __syncthreads();
  }
  long cz = (long)z * sC;
  int li = (l >> 4) * 4, lj = l & 15;
#pragma unroll
  for (int fm = 0; fm < 4; ++fm)
#pragma unroll
    for (int fn = 0; fn < FN; ++fn) {
      long ib = i0 + wr * 64 + fm * 16 + li;
      long j  = j0 + wc * WN + fn * 16 + lj;
#pragma unroll
      for (int r = 0; r < 4; ++r) {
        float v = acc[fm][fn][r];
        if (BIASCOL) v += bias[j];
        if (RELU)    v = fmaxf(v, 0.f);
        Cout[cz + (ib + r) * ldc + j] = f2bf(v);
      }
    }
}

// ---------- PV GEMM, K-split x4, fused stat-combine + exp; bf16 partials ----------
__global__ __launch_bounds__(256) void pv_gemm(
    const unsigned short* __restrict__ E, const unsigned short* __restrict__ XV,
    const float2* __restrict__ part, unsigned short* __restrict__ xrp) {
  __shared__ unsigned short As[128 * 32];
  __shared__ unsigned short Bs[128 * 32];
  __shared__ float Ms[256];
  __shared__ float Ds[256];
  int z = blockIdx.z;
  int q = z >> 2, s = z & 3;
  const unsigned short* A = E + (long)q * NN * NN + s * 256;
  const unsigned short* B = XV + (long)(q & 3) * CN + s * 256;
  int t = threadIdx.x;
  {
    int n = s * 256 + t;
    float mx = -1e30f;
#pragma unroll
    for (int c = 0; c < 16; ++c) mx = fmaxf(mx, part[((long)q * 16 + c) * NN + n].x);
    float sm = 0.f;
#pragma unroll
    for (int c = 0; c < 16; ++c) {
      float2 p = part[((long)q * 16 + c) * NN + n];
      sm += p.y * __expf(p.x - mx);
    }
    Ms[t] = mx;
    Ds[t] = 1.f / sm;
  }
  int w = t >> 6, l = t & 63;
  int wr = w >> 1, wc = w & 1;
  long i0 = blockIdx.y * 128, j0 = blockIdx.x * 128;
  f32x4 acc[4][4];
#pragma unroll
  for (int a = 0; a < 4; ++a)
#pragma unroll
    for (int b = 0; b < 4; ++b) acc[a][b] = (f32x4){0.f, 0.f, 0.f, 0.f};
  int lr = l & 15, lk = (l >> 4) * 8;
  int ar = t >> 1, ah = (t & 1) * 16;
  __syncthreads();
  for (int k0 = 0; k0 < 256; k0 += 32) {
#pragma unroll
    for (int it = 0; it < 2; ++it) {
      int chunk = t + it * 256;
      int row = chunk >> 2, kq = chunk & 3;
      gload_lds16(B + (j0 + row) * 1024L + k0 + kq * 8, &Bs[chunk * 8]);
    }
    u16x8 e0 = *(const u16x8*)&A[(i0 + ar) * 1024L + k0 + ah];
    u16x8 e1 = *(const u16x8*)&A[(i0 + ar) * 1024L + k0 + ah + 8];
    u16x8 p0, p1;
#pragma unroll
    for (int j = 0; j < 8; ++j) {
      int n = k0 + ah + j;
      p0[j] = f2bf(__expf(bf2f(e0[j]) - Ms[n]) * Ds[n]);
    }
#pragma unroll
    for (int j = 0; j < 8; ++j) {
      int n = k0 + ah + 8 + j;
      p1[j] = f2bf(__expf(bf2f(e1[j]) - Ms[n]) * Ds[n]);
    }
    *(u16x8*)&As[ar * 32 + ah]     = p0;
    *(u16x8*)&As[ar * 32 + ah + 8] = p1;
    __syncthreads();
    short8 af[4], bfr[4];
#pragma unroll
    for (int f = 0; f < 4; ++f) af[f]  = *(const short8*)&As[(wr * 64 + f * 16 + lr) * 32 + lk];
#pragma unroll
    for (int f = 0; f < 4; ++f) bfr[f] = *(const short8*)&Bs[(wc * 64 + f * 16 + lr) * 32 + lk];
#pragma unroll
    for (int fm = 0; fm < 4; ++fm)
#pragma unroll
      for (int fn = 0; fn < 4; ++fn)
        acc[fm][fn] = __builtin_amdgcn_mfma_f32_16x16x32_bf16(af[fm], bfr[fn], acc[fm][fn], 0, 0, 0);
    __syncthreads();
  }
  long cz = (long)(s * 12 + q) << 18;
  int li = (l >> 4) * 4, lj = l & 15;
#pragma unroll
  for (int fm = 0; fm < 4; ++fm)
#pragma unroll
    for (int fn = 0; fn < 4; ++fn) {
      long ib = i0 + wr * 64 + fm * 16 + li;
      long j  = j0 + wc * 64 + fn * 16 + lj;
#pragma unroll
      for (int r = 0; r < 4; ++r)
        xrp[cz + (ib + r) * 256 + j] = f2bf(acc[fm][fn][r] * (1.f / 16.f));
    }
}

// ---------- mix (reshape-mean over 12 bf16 partials) + residual + LN1 ----------
__global__ __launch_bounds__(256) void mix_ln1(
    const unsigned short* __restrict__ xT, const unsigned short* __restrict__ xrp,
    const float* __restrict__ g, const float* __restrict__ bb,
    unsigned short* __restrict__ h_bf) {
  __shared__ float r1[4], r2[4];
  int bn = blockIdx.x;
  int i = bn >> 10, n = bn & 1023;
  int c = threadIdx.x;
  long no = (long)n * CC + c;
  float a = 0.f;
#pragma unroll
  for (int j = 0; j < 3; ++j)
#pragma unroll
    for (int s = 0; s < 4; ++s)
      a += bf2f(xrp[((long)(s * 12 + 3 * i + j) << 18) + no]);
  float v = bf2f(xT[(long)i * CN + no]) + a * (1.f / 3.f);
  float sS = v, s2 = v * v;
#pragma unroll
  for (int m = 32; m; m >>= 1) { sS += __shfl_xor(sS, m); s2 += __shfl_xor(s2, m); }
  if ((c & 63) == 0) { r1[c >> 6] = sS; r2[c >> 6] = s2; }
  __syncthreads();
  float mu = (r1[0] + r1[1] + r1[2] + r1[3]) * (1.f / 256.f);
  float var = (r2[0] + r2[1] + r2[2] + r2[3]) * (1.f / 256.f) - mu * mu;
  float o = (v - mu) * rsqrtf(var + 1e-6f) * g[c] + bb[c];
  h_bf[(long)bn * CC + c] = f2bf(o);
}

// ---------- combine MLP2 bf16 partials + bias + residual + LN2 + relu + transpose ----------
__global__ __launch_bounds__(256) void ln2t(
    const unsigned short* __restrict__ pm, const unsigned short* __restrict__ h_bf,
    const float* __restrict__ b2, const float* __restrict__ g,
    const float* __restrict__ bb, float* __restrict__ out) {
  __shared__ float tile[16][261];
  __shared__ float smu[16], srs[16];
  int i = blockIdx.y, n0 = blockIdx.x * 16;
  int t = threadIdx.x;
  float bc = b2[t];
#pragma unroll
  for (int r = 0; r < 16; ++r) {
    long row = (long)i * NN + n0 + r;
    float v = bc + bf2f(h_bf[row * CC + t]);
#pragma unroll
    for (int s = 0; s < 4; ++s) v += bf2f(pm[((long)s << 20) + row * CC + t]);
    tile[r][t] = v;
  }
  __syncthreads();
  int w = t >> 6, l = t & 63;
#pragma unroll
  for (int rr = 0; rr < 4; ++rr) {
    int r = w * 4 + rr;
    float s = 0.f, s2 = 0.f;
#pragma unroll
    for (int k = 0; k < 4; ++k) { float v = tile[r][l + 64 * k]; s += v; s2 += v * v; }
#pragma unroll
    for (int m = 32; m; m >>= 1) { s += __shfl_xor(s, m); s2 += __shfl_xor(s2, m); }
    if (l == 0) {
      float mu = s * (1.f / 256.f);
      float var = s2 * (1.f / 256.f) - mu * mu;
      smu[r] = mu; srs[r] = rsqrtf(var + 1e-6f);
    }
  }
  __syncthreads();
#pragma unroll
  for (int k = 0; k < 16; ++k) {
    int nn = t & 15, c = (t >> 4) + 16 * k;
    float v = (tile[nn][c] - smu[nn]) * srs[nn] * g[c] + bb[c];
    out[((long)i * CC + c) * NN + n0 + nn] = fmaxf(v, 0.f);
  }
}

extern "C" void kernel_launch(void* const* d_in, const int* in_sizes, int n_in,
                              void* d_out, int out_size, void* d_ws, size_t ws_size,
                              hipStream_t stream) {
  const float* x   = (const float*)d_in[0];
  const float* Wq  = (const float*)d_in[1];
  const float* Wk  = (const float*)d_in[2];
  const float* Wv  = (const float*)d_in[3];
  const float* bv  = (const float*)d_in[4];
  const float* g1  = (const float*)d_in[5];
  const float* b1v = (const float*)d_in[6];
  const float* W1  = (const float*)d_in[7];
  const float* b1m = (const float*)d_in[8];
  const float* W2  = (const float*)d_in[9];
  const float* b2m = (const float*)d_in[10];
  const float* g2  = (const float*)d_in[11];
  const float* b2v = (const float*)d_in[12];
  float* out = (float*)d_out;

  char* base = (char*)d_ws;
  // [0,24MB): E_bf; reused after pv: h_bf [0,2), hid_bf [2,10)
  unsigned short* E_bf   = (unsigned short*)base;
  unsigned short* h_bf   = (unsigned short*)base;
  unsigned short* hid_bf = (unsigned short*)(base + (2u << 20));
  size_t off = 24u << 20;
  unsigned short* xrp    = (unsigned short*)(base + off); off += 25165824;  // 24MB
  unsigned short* p_mlp  = (unsigned short*)(base + off); off += 8388608;   // 8MB
  unsigned short* wv_bf  = (unsigned short*)(base + off); off += 131072;
  unsigned short* w1_bf  = (unsigned short*)(base + off); off += 524288;
  unsigned short* w2_bf  = (unsigned short*)(base + off); off += 524288;
  unsigned short* xt_bf  = (unsigned short*)(base + off); off += 2097152;
  unsigned short* xqt_bf = (unsigned short*)(base + off); off += 6291456;
  unsigned short* xkt_bf = (unsigned short*)(base + off); off += 2097152;
  unsigned short* xv_bf  = (unsigned short*)(base + off); off += 2097152;
  float2* part           = (float2*)(base + off);         off += 1572864;

  // 1. prep: q/k proj (+passthrough, +xT tiles) (2048) + convert (576)
  prep_kernel<<<2624, 256, 0, stream>>>(x, Wq, Wk, (const float4*)Wv,
      (const float4*)W1, (const float4*)W2, wv_bf, w1_bf, w2_bf,
      xt_bf, xqt_bf, xkt_bf, out);
  // 2. attention GEMMs: xv (64 blocks) + energy/stats (768 blocks)
  attn_gemm<<<832, 256, 0, stream>>>(xkt_bf, xqt_bf, wv_bf, xt_bf,
      bv, E_bf, xv_bf, part);
  // 3. PV (K-split x4) with fused stat-combine + exp -> xrp bf16
  pv_gemm<<<dim3(2, 8, 48), 256, 0, stream>>>(E_bf, xv_bf, part, xrp);
  // 4. mix + LN1 -> h_bf
  mix_ln1<<<4096, 256, 0, stream>>>(xt_bf, xrp, g1, b1v, h_bf);
  // 5. hid = relu(h @ W1^T + b1) -> bf16, 128x64 tiles (512 blocks)
  mgemm<64,1,1><<<dim3(16, 32, 1), 256, 0, stream>>>(
      h_bf, w1_bf, hid_bf, b1m,
      256, 256, 1024, 256, 0L, 1, 0L, 1, 0L);
  // 6. MLP2 partials (K-split x4), 128x64 tiles (512 blocks) -> bf16
  mgemm<64,0,0><<<dim3(4, 32, 4), 256, 0, stream>>>(
      hid_bf, w2_bf, p_mlp, nullptr,
      1024, 1024, 256, 256, 256L, 4, 256L, 4, 1048576L);
  // 7. combine + bias + residual + LN2 + relu + transpose -> out[0..3]
  ln2t<<<dim3(64, 4), 256, 0, stream>>>(p_mlp, h_bf, b2m, g2, b2v, out);
}

// Round 12
// 171.801 us; speedup vs baseline: 1.0288x; 1.0288x over previous
//
#include <hip/hip_runtime.h>

#define CC 256
#define NN 1024
#define CN (CC*NN)

typedef __attribute__((ext_vector_type(8))) short short8;
typedef __attribute__((ext_vector_type(8))) unsigned short u16x8;
typedef __attribute__((ext_vector_type(4))) float f32x4;

__device__ __forceinline__ unsigned short f2bf(float x) {
  unsigned u = __float_as_uint(x);
  u = u + 0x7fffu + ((u >> 16) & 1u);
  return (unsigned short)(u >> 16);
}
__device__ __forceinline__ float bf2f(unsigned short b) {
  return __uint_as_float(((unsigned)b) << 16);
}
__device__ __forceinline__ void gload_lds16(const unsigned short* g, unsigned short* l) {
  __builtin_amdgcn_global_load_lds(
      (const __attribute__((address_space(1))) unsigned short*)g,
      (__attribute__((address_space(3))) unsigned short*)l, 16, 0, 0);
}

// ---------- prep: q/k proj (z<12: +passthrough out; z>=12: +xT tile), W convert ----------
__global__ __launch_bounds__(256) void prep_kernel(
    const float* __restrict__ x, const float* __restrict__ Wq,
    const float* __restrict__ Wk, const float4* __restrict__ Wv,
    const float4* __restrict__ W1, const float4* __restrict__ W2,
    unsigned short* __restrict__ wv_bf,
    unsigned short* __restrict__ w1_bf, unsigned short* __restrict__ w2_bf,
    unsigned short* __restrict__ xT, unsigned short* __restrict__ xqT,
    unsigned short* __restrict__ xkT, float* __restrict__ out) {
  __shared__ float shbuf[6464];   // Ws 64x65 + xs 64x36 = 6464 floats = 25.9KB
  int bz = blockIdx.x, t = threadIdx.x;
  if (bz < 2048) {
    float (*Ws)[65] = (float(*)[65])shbuf;               // 64x65
    float (*xs)[36] = (float(*)[36])(shbuf + 64 * 65);   // 64x36
    int z = bz >> 7, g = (bz >> 5) & 3, n0 = (bz & 31) * 32;
    const float* src; const float* W; unsigned short* dst;
    float* po = nullptr;
    int b = 0;
    if (z < 12) {
      src = x + (long)(4 + z) * CN; W = Wq; dst = xqT + (long)z * CN;
      po = out + (long)(4 + z) * CN;
    } else {
      b = z - 12;
      src = x + (long)b * CN; W = Wk; dst = xkT + (long)b * CN;
    }
    int tr = t >> 6, tc = t & 63;
#pragma unroll
    for (int r = 0; r < 16; ++r) {
      int i = tr + r * 4;
      Ws[i][tc] = W[(g * 64 + i) * 64 + tc];
    }
#pragma unroll
    for (int r = 0; r < 8; ++r) {
      int i = r * 8 + (t >> 5);
      int col = t & 31;
      float v = src[(long)(g * 64 + i) * NN + n0 + col];
      xs[i][col] = v;
      if (po) po[(long)(g * 64 + i) * NN + n0 + col] = v;
    }
    __syncthreads();
    int o = tc, qd = tr;   // qd uniform per wave
    float acc[8];
#pragma unroll
    for (int k = 0; k < 8; ++k) acc[k] = 0.f;
    for (int i = 0; i < 64; ++i) {
      float w = Ws[o][i];
      const float4* xr4 = (const float4*)&xs[i][qd * 8];
      float4 a0 = xr4[0], a1 = xr4[1];
      acc[0] += w * a0.x; acc[1] += w * a0.y; acc[2] += w * a0.z; acc[3] += w * a0.w;
      acc[4] += w * a1.x; acc[5] += w * a1.y; acc[6] += w * a1.z; acc[7] += w * a1.w;
    }
#pragma unroll
    for (int k = 0; k < 8; ++k)
      dst[(long)(n0 + qd * 8 + k) * CC + g * 64 + o] = f2bf(acc[k]);
    if (z >= 12) {
      int nl = t >> 3;            // 0..31
      int coff = (t & 7) * 8;     // 0..56
      u16x8 v8;
#pragma unroll
      for (int k = 0; k < 8; ++k) v8[k] = f2bf(xs[coff + k][nl]);
      *(u16x8*)&xT[(long)b * CN + (long)(n0 + nl) * CC + g * 64 + coff] = v8;
    }
  } else {
    // convert Wv (16384) + W1 (65536) + W2 (65536) = 147456 float4s
    int id = (bz - 2048) * 256 + t;
    const float4* s; unsigned short* d; int k;
    if (id < 16384)      { s = Wv; d = wv_bf; k = id; }
    else if (id < 81920) { s = W1; d = w1_bf; k = id - 16384; }
    else                 { s = W2; d = w2_bf; k = id - 81920; }
    float4 v = s[k];
    ushort4 o; o.x = f2bf(v.x); o.y = f2bf(v.y); o.z = f2bf(v.z); o.w = f2bf(v.w);
    *(ushort4*)&d[k * 4] = o;
  }
}

// ---------- attention GEMM, BK=64 + XOR-swizzled staging ----------
// z<64 -> xv projection; z>=64 -> energy + stats
__global__ __launch_bounds__(256) void attn_gemm(
    const unsigned short* __restrict__ xkt, const unsigned short* __restrict__ xqt,
    const unsigned short* __restrict__ wv, const unsigned short* __restrict__ xt,
    const float* __restrict__ bv, unsigned short* __restrict__ E,
    unsigned short* __restrict__ xv, float2* __restrict__ part) {
  __shared__ unsigned short As[128 * 64];
  __shared__ unsigned short Bs[128 * 64];
  int z = blockIdx.x;
  const unsigned short *A, *B;
  unsigned short* Co;
  long i0, j0;
  int q = 0;
  bool isXV = z < 64;
  if (isXV) {
    int b = z >> 4, r = z & 15;
    i0 = (r >> 3) * 128; j0 = (r & 7) * 128;
    A = wv; B = xt + (long)b * CN; Co = xv + (long)b * CN;
  } else {
    int ze = z - 64;
    q = ze >> 6; int r = ze & 63;
    i0 = (r >> 3) * 128; j0 = (r & 7) * 128;
    A = xkt + (long)(q & 3) * CN; B = xqt + (long)q * CN;
    Co = E + (long)q * NN * NN;
  }
  int t = threadIdx.x, w = t >> 6, l = t & 63;
  int wr = w >> 1, wc = w & 1;
  f32x4 acc[4][4];
#pragma unroll
  for (int a = 0; a < 4; ++a)
#pragma unroll
    for (int b = 0; b < 4; ++b) acc[a][b] = (f32x4){0.f, 0.f, 0.f, 0.f};
  int lr = l & 15, hi = l >> 4;
  for (int k0 = 0; k0 < 256; k0 += 64) {
#pragma unroll
    for (int it = 0; it < 4; ++it) {
      int chunk = t + it * 256;          // 0..1023
      int row = chunk >> 3, kq = chunk & 7;
      int kqs = kq ^ (row & 7);          // pre-swizzled source granule
      gload_lds16(A + (i0 + row) * 256L + k0 + kqs * 8, &As[chunk * 8]);
      gload_lds16(B + (j0 + row) * 256L + k0 + kqs * 8, &Bs[chunk * 8]);
    }
    __syncthreads();
#pragma unroll
    for (int kk = 0; kk < 2; ++kk) {
      short8 af[4], bfr[4];
#pragma unroll
      for (int f = 0; f < 4; ++f) {
        int rowa = wr * 64 + f * 16 + lr;
        af[f]  = *(const short8*)&As[rowa * 64 + (((kk * 4 + hi) ^ (rowa & 7)) * 8)];
        int rowb = wc * 64 + f * 16 + lr;
        bfr[f] = *(const short8*)&Bs[rowb * 64 + (((kk * 4 + hi) ^ (rowb & 7)) * 8)];
      }
#pragma unroll
      for (int fm = 0; fm < 4; ++fm)
#pragma unroll
        for (int fn = 0; fn < 4; ++fn)
          acc[fm][fn] = __builtin_amdgcn_mfma_f32_16x16x32_bf16(af[fm], bfr[fn], acc[fm][fn], 0, 0, 0);
    }
    __syncthreads();
  }
  int li = hi * 4, lj = l & 15;
#pragma unroll
  for (int fm = 0; fm < 4; ++fm)
#pragma unroll
    for (int fn = 0; fn < 4; ++fn) {
      long ib = i0 + wr * 64 + fm * 16 + li;
      long j  = j0 + wc * 64 + fn * 16 + lj;
#pragma unroll
      for (int r = 0; r < 4; ++r) {
        float v = acc[fm][fn][r];
        if (isXV) v += bv[ib + r];
        Co[(ib + r) * 1024 + j] = f2bf(v);
      }
    }
  if (!isXV) {
    int chunk = (int)(i0 >> 6) + wr;
#pragma unroll
    for (int fn = 0; fn < 4; ++fn) {
      float mx = -1e30f;
#pragma unroll
      for (int fm = 0; fm < 4; ++fm)
#pragma unroll
        for (int r = 0; r < 4; ++r) mx = fmaxf(mx, acc[fm][fn][r]);
      mx = fmaxf(mx, __shfl_xor(mx, 16));
      mx = fmaxf(mx, __shfl_xor(mx, 32));
      float sm = 0.f;
#pragma unroll
      for (int fm = 0; fm < 4; ++fm)
#pragma unroll
        for (int r = 0; r < 4; ++r) sm += __expf(acc[fm][fn][r] - mx);
      sm += __shfl_xor(sm, 16);
      sm += __shfl_xor(sm, 32);
      if (l < 16) {
        long n = j0 + wc * 64 + fn * 16 + l;
        part[((long)q * 16 + chunk) * NN + n] = make_float2(mx, sm);
      }
    }
  }
}

// ---------- bf16 MFMA GEMM, 128xBN tile, BK=64 + XOR-swizzled staging (MLP shapes) ----------
template<int BN, int BIASCOL, int RELU>
__global__ __launch_bounds__(256) void mgemm(
    const unsigned short* __restrict__ A, const unsigned short* __restrict__ B,
    unsigned short* __restrict__ Cout, const float* __restrict__ bias,
    int lda, int ldb, int ldc, int K,
    long sA, int amod, long sB, int bmod, long sC) {
  __shared__ unsigned short As[128 * 64];
  __shared__ unsigned short Bs[BN * 64];
  int z = blockIdx.z;
  A += (long)(z % amod) * sA;
  B += (long)(z % bmod) * sB;
  int t = threadIdx.x, w = t >> 6, l = t & 63;
  int wr = w >> 1, wc = w & 1;
  const int WN = BN / 2, FN = BN / 32;
  long i0 = blockIdx.y * 128, j0 = blockIdx.x * BN;
  f32x4 acc[4][FN];
#pragma unroll
  for (int a = 0; a < 4; ++a)
#pragma unroll
    for (int b = 0; b < FN; ++b) acc[a][b] = (f32x4){0.f, 0.f, 0.f, 0.f};
  int lr = l & 15, hi = l >> 4;
  for (int k0 = 0; k0 < K; k0 += 64) {
#pragma unroll
    for (int it = 0; it < 4; ++it) {
      int chunk = t + it * 256;
      int row = chunk >> 3, kq = chunk & 7;
      int kqs = kq ^ (row & 7);
      gload_lds16(A + (i0 + row) * (long)lda + k0 + kqs * 8, &As[chunk * 8]);
    }
#pragma unroll
    for (int it = 0; it < BN / 32; ++it) {
      int chunk = t + it * 256;          // 0..BN*8-1
      int row = chunk >> 3, kq = chunk & 7;
      int kqs = kq ^ (row & 7);
      gload_lds16(B + (j0 + row) * (long)ldb + k0 + kqs * 8, &Bs[chunk * 8]);
    }
    __syncthreads();
#pragma unroll
    for (int kk = 0; kk < 2; ++kk) {
      short8 af[4], bfr[FN];
#pragma unroll
      for (int f = 0; f < 4; ++f) {
        int rowa = wr * 64 + f * 16 + lr;
        af[f] = *(const short8*)&As[rowa * 64 + (((kk * 4 + hi) ^ (rowa & 7)) * 8)];
      }
#pragma unroll
      for (int f = 0; f < FN; ++f) {
        int rowb = wc * WN + f * 16 + lr;
        bfr[f] = *(const short8*)&Bs[rowb * 64 + (((kk * 4 + hi) ^ (rowb & 7)) * 8)];
      }
#pragma unroll
      for (int fm = 0; fm < 4; ++fm)
#pragma unroll
        for (int fn = 0; fn < FN; ++fn)
          acc[fm][fn] = __builtin_amdgcn_mfma_f32_16x16x32_bf16(af[fm], bfr[fn], acc[fm][fn], 0, 0, 0);
    }
    __syncthreads();
  }
  long cz = (long)z * sC;
  int li = hi * 4, lj = l & 15;
#pragma unroll
  for (int fm = 0; fm < 4; ++fm)
#pragma unroll
    for (int fn = 0; fn < FN; ++fn) {
      long ib = i0 + wr * 64 + fm * 16 + li;
      long j  = j0 + wc * WN + fn * 16 + lj;
#pragma unroll
      for (int r = 0; r < 4; ++r) {
        float v = acc[fm][fn][r];
        if (BIASCOL) v += bias[j];
        if (RELU)    v = fmaxf(v, 0.f);
        Cout[cz + (ib + r) * ldc + j] = f2bf(v);
      }
    }
}

// ---------- PV GEMM, K-split x4, fused stat-combine + exp; bf16 partials (unchanged) ----------
__global__ __launch_bounds__(256) void pv_gemm(
    const unsigned short* __restrict__ E, const unsigned short* __restrict__ XV,
    const float2* __restrict__ part, unsigned short* __restrict__ xrp) {
  __shared__ unsigned short As[128 * 32];
  __shared__ unsigned short Bs[128 * 32];
  __shared__ float Ms[256];
  __shared__ float Ds[256];
  int z = blockIdx.z;
  int q = z >> 2, s = z & 3;
  const unsigned short* A = E + (long)q * NN * NN + s * 256;
  const unsigned short* B = XV + (long)(q & 3) * CN + s * 256;
  int t = threadIdx.x;
  {
    int n = s * 256 + t;
    float mx = -1e30f;
#pragma unroll
    for (int c = 0; c < 16; ++c) mx = fmaxf(mx, part[((long)q * 16 + c) * NN + n].x);
    float sm = 0.f;
#pragma unroll
    for (int c = 0; c < 16; ++c) {
      float2 p = part[((long)q * 16 + c) * NN + n];
      sm += p.y * __expf(p.x - mx);
    }
    Ms[t] = mx;
    Ds[t] = 1.f / sm;
  }
  int w = t >> 6, l = t & 63;
  int wr = w >> 1, wc = w & 1;
  long i0 = blockIdx.y * 128, j0 = blockIdx.x * 128;
  f32x4 acc[4][4];
#pragma unroll
  for (int a = 0; a < 4; ++a)
#pragma unroll
    for (int b = 0; b < 4; ++b) acc[a][b] = (f32x4){0.f, 0.f, 0.f, 0.f};
  int lr = l & 15, lk = (l >> 4) * 8;
  int ar = t >> 1, ah = (t & 1) * 16;
  __syncthreads();
  for (int k0 = 0; k0 < 256; k0 += 32) {
#pragma unroll
    for (int it = 0; it < 2; ++it) {
      int chunk = t + it * 256;
      int row = chunk >> 2, kq = chunk & 3;
      gload_lds16(B + (j0 + row) * 1024L + k0 + kq * 8, &Bs[chunk * 8]);
    }
    u16x8 e0 = *(const u16x8*)&A[(i0 + ar) * 1024L + k0 + ah];
    u16x8 e1 = *(const u16x8*)&A[(i0 + ar) * 1024L + k0 + ah + 8];
    u16x8 p0, p1;
#pragma unroll
    for (int j = 0; j < 8; ++j) {
      int n = k0 + ah + j;
      p0[j] = f2bf(__expf(bf2f(e0[j]) - Ms[n]) * Ds[n]);
    }
#pragma unroll
    for (int j = 0; j < 8; ++j) {
      int n = k0 + ah + 8 + j;
      p1[j] = f2bf(__expf(bf2f(e1[j]) - Ms[n]) * Ds[n]);
    }
    *(u16x8*)&As[ar * 32 + ah]     = p0;
    *(u16x8*)&As[ar * 32 + ah + 8] = p1;
    __syncthreads();
    short8 af[4], bfr[4];
#pragma unroll
    for (int f = 0; f < 4; ++f) af[f]  = *(const short8*)&As[(wr * 64 + f * 16 + lr) * 32 + lk];
#pragma unroll
    for (int f = 0; f < 4; ++f) bfr[f] = *(const short8*)&Bs[(wc * 64 + f * 16 + lr) * 32 + lk];
#pragma unroll
    for (int fm = 0; fm < 4; ++fm)
#pragma unroll
      for (int fn = 0; fn < 4; ++fn)
        acc[fm][fn] = __builtin_amdgcn_mfma_f32_16x16x32_bf16(af[fm], bfr[fn], acc[fm][fn], 0, 0, 0);
    __syncthreads();
  }
  long cz = (long)(s * 12 + q) << 18;
  int li = (l >> 4) * 4, lj = l & 15;
#pragma unroll
  for (int fm = 0; fm < 4; ++fm)
#pragma unroll
    for (int fn = 0; fn < 4; ++fn) {
      long ib = i0 + wr * 64 + fm * 16 + li;
      long j  = j0 + wc * 64 + fn * 16 + lj;
#pragma unroll
      for (int r = 0; r < 4; ++r)
        xrp[cz + (ib + r) * 256 + j] = f2bf(acc[fm][fn][r] * (1.f / 16.f));
    }
}

// ---------- mix (reshape-mean over 12 bf16 partials) + residual + LN1 ----------
__global__ __launch_bounds__(256) void mix_ln1(
    const unsigned short* __restrict__ xT, const unsigned short* __restrict__ xrp,
    const float* __restrict__ g, const float* __restrict__ bb,
    unsigned short* __restrict__ h_bf) {
  __shared__ float r1[4], r2[4];
  int bn = blockIdx.x;
  int i = bn >> 10, n = bn & 1023;
  int c = threadIdx.x;
  long no = (long)n * CC + c;
  float a = 0.f;
#pragma unroll
  for (int j = 0; j < 3; ++j)
#pragma unroll
    for (int s = 0; s < 4; ++s)
      a += bf2f(xrp[((long)(s * 12 + 3 * i + j) << 18) + no]);
  float v = bf2f(xT[(long)i * CN + no]) + a * (1.f / 3.f);
  float sS = v, s2 = v * v;
#pragma unroll
  for (int m = 32; m; m >>= 1) { sS += __shfl_xor(sS, m); s2 += __shfl_xor(s2, m); }
  if ((c & 63) == 0) { r1[c >> 6] = sS; r2[c >> 6] = s2; }
  __syncthreads();
  float mu = (r1[0] + r1[1] + r1[2] + r1[3]) * (1.f / 256.f);
  float var = (r2[0] + r2[1] + r2[2] + r2[3]) * (1.f / 256.f) - mu * mu;
  float o = (v - mu) * rsqrtf(var + 1e-6f) * g[c] + bb[c];
  h_bf[(long)bn * CC + c] = f2bf(o);
}

// ---------- combine MLP2 bf16 partials + bias + residual + LN2 + relu + transpose ----------
__global__ __launch_bounds__(256) void ln2t(
    const unsigned short* __restrict__ pm, const unsigned short* __restrict__ h_bf,
    const float* __restrict__ b2, const float* __restrict__ g,
    const float* __restrict__ bb, float* __restrict__ out) {
  __shared__ float tile[16][261];
  __shared__ float smu[16], srs[16];
  int i = blockIdx.y, n0 = blockIdx.x * 16;
  int t = threadIdx.x;
  float bc = b2[t];
#pragma unroll
  for (int r = 0; r < 16; ++r) {
    long row = (long)i * NN + n0 + r;
    float v = bc + bf2f(h_bf[row * CC + t]);
#pragma unroll
    for (int s = 0; s < 4; ++s) v += bf2f(pm[((long)s << 20) + row * CC + t]);
    tile[r][t] = v;
  }
  __syncthreads();
  int w = t >> 6, l = t & 63;
#pragma unroll
  for (int rr = 0; rr < 4; ++rr) {
    int r = w * 4 + rr;
    float s = 0.f, s2 = 0.f;
#pragma unroll
    for (int k = 0; k < 4; ++k) { float v = tile[r][l + 64 * k]; s += v; s2 += v * v; }
#pragma unroll
    for (int m = 32; m; m >>= 1) { s += __shfl_xor(s, m); s2 += __shfl_xor(s2, m); }
    if (l == 0) {
      float mu = s * (1.f / 256.f);
      float var = s2 * (1.f / 256.f) - mu * mu;
      smu[r] = mu; srs[r] = rsqrtf(var + 1e-6f);
    }
  }
  __syncthreads();
#pragma unroll
  for (int k = 0; k < 16; ++k) {
    int nn = t & 15, c = (t >> 4) + 16 * k;
    float v = (tile[nn][c] - smu[nn]) * srs[nn] * g[c] + bb[c];
    out[((long)i * CC + c) * NN + n0 + nn] = fmaxf(v, 0.f);
  }
}

extern "C" void kernel_launch(void* const* d_in, const int* in_sizes, int n_in,
                              void* d_out, int out_size, void* d_ws, size_t ws_size,
                              hipStream_t stream) {
  const float* x   = (const float*)d_in[0];
  const float* Wq  = (const float*)d_in[1];
  const float* Wk  = (const float*)d_in[2];
  const float* Wv  = (const float*)d_in[3];
  const float* bv  = (const float*)d_in[4];
  const float* g1  = (const float*)d_in[5];
  const float* b1v = (const float*)d_in[6];
  const float* W1  = (const float*)d_in[7];
  const float* b1m = (const float*)d_in[8];
  const float* W2  = (const float*)d_in[9];
  const float* b2m = (const float*)d_in[10];
  const float* g2  = (const float*)d_in[11];
  const float* b2v = (const float*)d_in[12];
  float* out = (float*)d_out;

  char* base = (char*)d_ws;
  // [0,24MB): E_bf; reused after pv: h_bf [0,2), hid_bf [2,10)
  unsigned short* E_bf   = (unsigned short*)base;
  unsigned short* h_bf   = (unsigned short*)base;
  unsigned short* hid_bf = (unsigned short*)(base + (2u << 20));
  size_t off = 24u << 20;
  unsigned short* xrp    = (unsigned short*)(base + off); off += 25165824;  // 24MB
  unsigned short* p_mlp  = (unsigned short*)(base + off); off += 8388608;   // 8MB
  unsigned short* wv_bf  = (unsigned short*)(base + off); off += 131072;
  unsigned short* w1_bf  = (unsigned short*)(base + off); off += 524288;
  unsigned short* w2_bf  = (unsigned short*)(base + off); off += 524288;
  unsigned short* xt_bf  = (unsigned short*)(base + off); off += 2097152;
  unsigned short* xqt_bf = (unsigned short*)(base + off); off += 6291456;
  unsigned short* xkt_bf = (unsigned short*)(base + off); off += 2097152;
  unsigned short* xv_bf  = (unsigned short*)(base + off); off += 2097152;
  float2* part           = (float2*)(base + off);         off += 1572864;

  // 1. prep: q/k proj (+passthrough, +xT tiles) (2048) + convert (576)
  prep_kernel<<<2624, 256, 0, stream>>>(x, Wq, Wk, (const float4*)Wv,
      (const float4*)W1, (const float4*)W2, wv_bf, w1_bf, w2_bf,
      xt_bf, xqt_bf, xkt_bf, out);
  // 2. attention GEMMs: xv (64 blocks) + energy/stats (768 blocks), BK=64
  attn_gemm<<<832, 256, 0, stream>>>(xkt_bf, xqt_bf, wv_bf, xt_bf,
      bv, E_bf, xv_bf, part);
  // 3. PV (K-split x4) with fused stat-combine + exp -> xrp bf16
  pv_gemm<<<dim3(2, 8, 48), 256, 0, stream>>>(E_bf, xv_bf, part, xrp);
  // 4. mix + LN1 -> h_bf
  mix_ln1<<<4096, 256, 0, stream>>>(xt_bf, xrp, g1, b1v, h_bf);
  // 5. hid = relu(h @ W1^T + b1) -> bf16, 128x64 tiles (512 blocks), BK=64
  mgemm<64,1,1><<<dim3(16, 32, 1), 256, 0, stream>>>(
      h_bf, w1_bf, hid_bf, b1m,
      256, 256, 1024, 256, 0L, 1, 0L, 1, 0L);
  // 6. MLP2 partials (K-split x4), 128x64 tiles (512 blocks), BK=64 -> bf16
  mgemm<64,0,0><<<dim3(4, 32, 4), 256, 0, stream>>>(
      hid_bf, w2_bf, p_mlp, nullptr,
      1024, 1024, 256, 256, 256L, 4, 256L, 4, 1048576L);
  // 7. combine + bias + residual + LN2 + relu + transpose -> out[0..3]
  ln2t<<<dim3(64, 4), 256, 0, stream>>>(p_mlp, h_bf, b2m, g2, b2v, out);
}